// Round 14
// baseline (7718.678 us; speedup 1.0000x reference)
//
#include <hip/hip_runtime.h>

#define H6   3072
#define TT   1000
#define NWG  192
#define NTHR 256

typedef short bf16x8 __attribute__((ext_vector_type(8)));
typedef float f32x4  __attribute__((ext_vector_type(4)));
typedef unsigned int u32x4 __attribute__((ext_vector_type(4)));

#define TAG64 0x8000800080008000ull

// ---- bf16 helpers ----
__device__ __forceinline__ unsigned short f2bf(float f) {   // RNE (weights only)
  unsigned u = __float_as_uint(f);
  return (unsigned short)((u + 0x7fffu + ((u >> 16) & 1u)) >> 16);
}
__device__ __forceinline__ float bf2f(unsigned short s) {
  return __uint_as_float(((unsigned)s) << 16);
}

// ---- workspace layout (bytes) ----
// Whi   : 2621440 bf16 = 5242880        @ 0
// Wlo   : 5242880                        @ 5242880
// ring  : 8 slots * 196608 B = 1572864   @ 10485760   (hi/lo interleaved)
// fc_v  : 512 f32 = 2048                 @ 12058624
#define WS_WLO 5242880
#define WS_RING 10485760
#define WS_FCV 12058624

// Ring slot layout (interleaved, as r6): region r: +r*32768B; chunk q: +q*2048B;
//   unit (b,g8): 32B at +b*128+g8*32 = {16B hi}{16B lo}.
// Protocol = r6 (best measured, 5614us): data-as-probe with per-ushort parity
//   tags; producer __hip_atomic_store u64 (r7/r10 nt REGRESSED: +36%;
//   r11 flag-spin REGRESSED: +18% -- every flag scheme adds a serial
//   coherence-visit, and serial visits are the cost, not poll traffic).
// ROUND-12 CHANGES (2): (a) software-pipelined probe -- the full load round
//   for step t+1 is issued right after the reduce barrier, so its flight
//   overlaps wave0's epilogue+publish instead of starting after them;
//   (b) hot spin (no s_sleep) -- retries reload only stale chunks, and the
//   idle-sleep may be inviting DPM downclock on this >90%-idle kernel.

// ============================ prep kernel ============================
__global__ void prep_kernel(
    const float* __restrict__ hn, const float* __restrict__ fixed_,
    const float* __restrict__ thal2alm_w, const float* __restrict__ thal2str_w,
    const float* __restrict__ alm2alm_w, const float* __restrict__ alm2str_w,
    const float* __restrict__ str2snr_w, const float* __restrict__ str2gpe_w,
    const float* __restrict__ gpe2stn_w, const float* __restrict__ stn2snr_w,
    const float* __restrict__ snr2thal_w,
    const float* __restrict__ fc1, const float* __restrict__ fc2,
    unsigned short* __restrict__ Whi, unsigned short* __restrict__ Wlo,
    unsigned short* __restrict__ ring, float* __restrict__ fc_vec)
{
  int gid = blockIdx.x * blockDim.x + threadIdx.x;
  int stride = gridDim.x * blockDim.x;
  const int nbt[6]  = {3,1,1,2,1,2};
  const int woff[6] = {0,786432,1048576,1310720,1835008,2097152};
  for (int idx = gid; idx < 2621440; idx += stride) {
    int u = idx >> 18;
    int t = (u<3)?0:((u<4)?1:((u<5)?2:((u<7)?3:((u<8)?4:5))));
    int local = idx - woff[t];
    int ktot = nbt[t] << 9;
    int j  = local / ktot;
    int kx = local - j*ktot;
    int bi = kx >> 9, kk = kx & 511;
    int src = j*512 + kk;
    float w;
    if (t == 0) {       // str rows: [str | thal | alm]
      if (bi == 0)      w = -fixed_[src];
      else if (bi == 1) w = (j >= 128 && j < 384) ? fmaxf(thal2str_w[src],0.f) : 0.f;
      else              w = (kk < 359) ? fmaxf(alm2str_w[src],0.f) : 0.f;
    } else if (t == 1)  w = (kk >= 256) ? -fmaxf(str2gpe_w[src],0.f) : 0.f;
    else if (t == 2)    w = -fmaxf(gpe2stn_w[src],0.f);
    else if (t == 3)    w = (bi == 0) ? ((kk < 256) ? -fmaxf(str2snr_w[src],0.f) : 0.f)
                                      : fmaxf(stn2snr_w[src],0.f);
    else if (t == 4)    w = -fmaxf(snr2thal_w[src],0.f);
    else                w = (bi == 0) ? fmaxf(thal2alm_w[src],0.f)
                                      : fmaxf(alm2alm_w[src],0.f) * ((kk < 359) ? 1.f : -1.f);
    unsigned short hi = f2bf(w);
    Whi[idx] = hi;
    Wlo[idx] = f2bf(w - bf2f(hi));
  }
  // poison slots 0-6: alternating tag bits -> any u64 has mixed parity
  for (int u = gid; u < 7*98304; u += stride)
    ring[u] = (u & 1) ? (unsigned short)0x0000 : (unsigned short)0x8000;
  // h0 = hn into slot 7 (interleaved layout), RTZ split, tag parity = 1
  for (int v = gid; v < 49152; v += stride) {
    int r    = v >> 13;
    int rem  = v & 8191;
    int q    = rem >> 9;
    int rem2 = rem & 511;
    int b    = rem2 >> 5;
    int ko   = rem2 & 31;
    int j    = (r << 9) + (q << 5) + ko;
    float val = hn[b * H6 + j];
    unsigned uh = __float_as_uint(val) >> 16;          // RTZ hi
    float lof = val - __uint_as_float(uh << 16);
    unsigned ul = __float_as_uint(lof) >> 16;          // RTZ lo (>=0)
    int off = r*16384 + q*1024 + b*64 + ((ko>>3)<<4) + (ko & 7);  // ushort idx
    ring[7*98304 + off]     = (unsigned short)(uh | 0x8000u);
    ring[7*98304 + off + 8] = (unsigned short)(ul | 0x8000u);
  }
  int wid = gid >> 6, lane = gid & 63;
  if (wid < 512) {
    float s = 0.f;
    for (int m = lane; m < 512; m += 64)
      s += fmaxf(fc1[(2560 + wid)*512 + m], 0.f) * fmaxf(fc2[m], 0.f);
    for (int off = 32; off; off >>= 1) s += __shfl_down(s, off);
    if (lane == 0) fc_vec[wid] = s;
  }
}

// ============================ scan kernel ============================
template<int NB>
__device__ __forceinline__ void scan_body(
    const float* __restrict__ inp, const float* __restrict__ hn,
    const float* __restrict__ inhib, const float* __restrict__ inp_weight,
    const unsigned short* __restrict__ Whi_g, const unsigned short* __restrict__ Wlo_g,
    unsigned short* __restrict__ ring, float* __restrict__ rnn_out,
    float* red, int type, int tile, int kb0, int kb1, int kb2, int woff)
{
  constexpr int NCW = NB * 4;                 // K-chunks (of 32) per wave
  constexpr unsigned FULLM = (NCW == 12) ? 0xFFFu : ((NCW == 8) ? 0xFFu : 0xFu);
  const int tid = threadIdx.x, lane = tid & 63, wave = tid >> 6;
  const int ktot = NB << 9;
  const int jb_local = tile << 4;
  const int jb_glob  = (type << 9) + jb_local;
  const int row = lane & 15, quad = lane >> 4;

  // ---- W fragments -> registers (pinned); per-chunk ring byte offsets ----
  bf16x8 wh[NCW], wl[NCW];
  int coff[NCW];                              // byte offset within a ring slot
  {
    const unsigned short* sh = Whi_g + woff + (jb_local + row) * ktot + (quad << 3);
    const unsigned short* sl = Wlo_g + woff + (jb_local + row) * ktot + (quad << 3);
    #pragma unroll
    for (int c = 0; c < NCW; ++c) {
      int gc = wave * NCW + c;                // global chunk 0..NB*16-1
      wh[c] = *(const bf16x8*)(sh + (gc << 5));
      wl[c] = *(const bf16x8*)(sl + (gc << 5));
      int bi = gc >> 4;
      int kbv = (bi == 0) ? kb0 : ((bi == 1) ? kb1 : kb2);
      coff[c] = kbv*32768 + (gc & 15)*2048 + row*128 + quad*32;
    }
  }
  #pragma unroll
  for (int c = 0; c < NCW; ++c)
    asm volatile("" : "+v"(wh[c]), "+v"(wl[c]));

  // ---- per-lane epilogue constants (C/D: col=b=lane&15, row=quad*4+r) ----
  const int b_ep = row;
  const bool has_inp = (type == 0) && (jb_local >= 128) && (jb_local < 384);
  const int jg0 = jb_glob + (quad << 2);
  const int jl0 = jb_local + (quad << 2);
  // producer store: byte offset of hi u64 within a slot (lo at +16)
  const int qs = jl0 >> 5, kos = jl0 & 31;
  const int st_off = type*32768 + qs*2048 + b_ep*128 + ((kos>>3)<<5) + ((kos&7)<<1);
  float hprev[4], dbase[4], iw[4][4];
  #pragma unroll
  for (int r = 0; r < 4; ++r) {
    int jgr = jg0 + r;
    hprev[r] = hn[b_ep * H6 + jgr];
    float tn = ((jgr >= 512 && jgr < 1536) || (jgr >= 2048 && jgr < 2560)) ? 1.f : 0.f;
    dbase[r] = inhib[b_ep * H6 + jgr] + tn;
    #pragma unroll
    for (int i = 0; i < 4; ++i)
      iw[r][i] = has_inp ? fmaxf(inp_weight[i * H6 + jgr], 0.f) : 0.f;
  }

  // ---- prologue: issue probe round for t=0 (slot 7, prep data, parity 1) ----
  u32x4 Bhi[NCW], Blo[NCW];
  {
    const char* sp = (const char*)ring + 7 * 196608;
    #pragma unroll
    for (int c = 0; c < NCW; ++c) {
      const char* pc = sp + coff[c];
      asm volatile("global_load_dwordx4 %0, %2, off sc0 sc1\n\t"
                   "global_load_dwordx4 %1, %2, off offset:16 sc0 sc1"
                   : "=&v"(Bhi[c]), "=&v"(Blo[c]) : "v"(pc) : "memory");
    }
  }
  unsigned e32 = 0x80008000u;                 // E(0) = parity 1 (prep)

  for (int t = 0; t < TT; ++t) {
    const char* slotp = (const char*)ring + ((t + 7) & 7) * 196608;

    float4 xi = {0.f, 0.f, 0.f, 0.f};
    if (wave == 0 && has_inp) xi = *(const float4*)(inp + (b_ep * TT + t) * 4);

    // ---- wait for in-flight probe; hot-retry only stale chunks ----
    unsigned todo = FULLM;
    bool first = true;
    for (;;) {
      if (!first) {
        #pragma unroll
        for (int c = 0; c < NCW; ++c) if ((todo >> c) & 1u) {
          const char* pc = slotp + coff[c];
          asm volatile("global_load_dwordx4 %0, %2, off sc0 sc1\n\t"
                       "global_load_dwordx4 %1, %2, off offset:16 sc0 sc1"
                       : "=&v"(Bhi[c]), "=&v"(Blo[c]) : "v"(pc) : "memory");
        }
      }
      asm volatile("s_waitcnt vmcnt(0)" ::: "memory");
      __builtin_amdgcn_sched_barrier(0);
      unsigned nt = 0;
      #pragma unroll
      for (int c = 0; c < NCW; ++c) if ((todo >> c) & 1u) {
        unsigned bad = ((Bhi[c][0] ^ e32) | (Bhi[c][1] ^ e32) |
                        (Bhi[c][2] ^ e32) | (Bhi[c][3] ^ e32) |
                        (Blo[c][0] ^ e32) | (Blo[c][1] ^ e32) |
                        (Blo[c][2] ^ e32) | (Blo[c][3] ^ e32)) & 0x80008000u;
        if (__any(bad != 0u)) nt |= 1u << c;
      }
      if (nt == 0) break;
      todo = nt;
      first = false;                          // hot spin: no s_sleep
    }
    // strip tags (clear bit15 of every ushort)
    #pragma unroll
    for (int c = 0; c < NCW; ++c) {
      Bhi[c] &= 0x7fff7fffu;
      Blo[c] &= 0x7fff7fffu;
    }

    f32x4 acc0 = {0,0,0,0}, acc1 = {0,0,0,0}, acc2 = {0,0,0,0};
    #pragma unroll
    for (int c = 0; c < NCW; ++c) {
      bf16x8 hb = __builtin_bit_cast(bf16x8, Bhi[c]);
      bf16x8 lb = __builtin_bit_cast(bf16x8, Blo[c]);
      acc0 = __builtin_amdgcn_mfma_f32_16x16x32_bf16(wh[c], hb, acc0, 0, 0, 0);
      acc1 = __builtin_amdgcn_mfma_f32_16x16x32_bf16(wh[c], lb, acc1, 0, 0, 0);
      acc2 = __builtin_amdgcn_mfma_f32_16x16x32_bf16(wl[c], hb, acc2, 0, 0, 0);
    }
    f32x4 acc = acc0 + acc1 + acc2;

    // ---- cross-wave reduce (double-buffered on t&1; single barrier/step) ----
    float* bank = red + (t & 1) * 768;
    if (wave) *(f32x4*)(bank + ((wave - 1) * 64 + lane) * 4) = acc;
    __syncthreads();

    // ---- PIPELINE: issue next step's probe round NOW (flight overlaps the
    //      epilogue+publish below). Own-region chunks will be stale until our
    //      own publish lands -- the retry loop above handles that. ----
    if (t + 1 < TT) {
      const char* spn = (const char*)ring + (t & 7) * 196608;
      #pragma unroll
      for (int c = 0; c < NCW; ++c) {
        const char* pc = spn + coff[c];
        asm volatile("global_load_dwordx4 %0, %2, off sc0 sc1\n\t"
                     "global_load_dwordx4 %1, %2, off offset:16 sc0 sc1"
                     : "=&v"(Bhi[c]), "=&v"(Blo[c]) : "v"(pc) : "memory");
      }
      e32 = ((t >> 3) & 1) ? 0x80008000u : 0u;   // E(t+1) = P(t)
    }

    if (wave == 0) {
      acc = acc + *(const f32x4*)(bank + lane * 4)
                + *(const f32x4*)(bank + (64 + lane) * 4)
                + *(const f32x4*)(bank + (128 + lane) * 4);
      float proj[4] = {0.f, 0.f, 0.f, 0.f};
      if (has_inp) {
        #pragma unroll
        for (int r = 0; r < 4; ++r)
          proj[r] = xi.x*iw[r][0] + xi.y*iw[r][1] + xi.z*iw[r][2] + xi.w*iw[r][3];
      }
      const unsigned long long ptag = ((t >> 3) & 1) ? TAG64 : 0ull;
      float4 hv4;
      unsigned long long ph = 0ull, pl = 0ull;
      #pragma unroll
      for (int r = 0; r < 4; ++r) {
        float pre = hprev[r] + 0.01f * (acc[r] + dbase[r] + proj[r] - hprev[r]);
        float hv = fmaxf(pre, 0.f);
        hprev[r] = hv;
        ((float*)&hv4)[r] = hv;
        unsigned uh = __float_as_uint(hv) >> 16;          // RTZ hi (hv>=0)
        float lof = hv - __uint_as_float(uh << 16);
        unsigned ul = __float_as_uint(lof) >> 16;         // RTZ lo (lof>=0)
        ph |= ((unsigned long long)uh) << (16 * r);
        pl |= ((unsigned long long)ul) << (16 * r);
      }
      ph |= ptag; pl |= ptag;
      char* outb = (char*)ring + (t & 7) * 196608 + st_off;
      __hip_atomic_store((unsigned long long*)outb, ph,
                         __ATOMIC_RELAXED, __HIP_MEMORY_SCOPE_AGENT);
      __hip_atomic_store((unsigned long long*)(outb + 16), pl,
                         __ATOMIC_RELAXED, __HIP_MEMORY_SCOPE_AGENT);
      // no drain, no flag: consumers detect arrival via the parity tags
      *(float4*)(rnn_out + (size_t)(b_ep * TT + t) * H6 + jg0) = hv4;
    }
  }
}

__global__ void __launch_bounds__(NTHR, 1) scan_kernel(
    const float* __restrict__ inp, const float* __restrict__ hn,
    const float* __restrict__ inhib, const float* __restrict__ inp_weight,
    const unsigned short* __restrict__ Whi_g, const unsigned short* __restrict__ Wlo_g,
    unsigned short* __restrict__ ring, float* __restrict__ rnn_out)
{
  __shared__ float red[2 * 768];
  int wg = blockIdx.x;
  int type = wg >> 5, tile = wg & 31;
  switch (type) {
    case 0: scan_body<3>(inp,hn,inhib,inp_weight,Whi_g,Wlo_g,ring,rnn_out,red,0,tile,0,4,5,0);       break;
    case 1: scan_body<1>(inp,hn,inhib,inp_weight,Whi_g,Wlo_g,ring,rnn_out,red,1,tile,0,0,0,786432);  break;
    case 2: scan_body<1>(inp,hn,inhib,inp_weight,Whi_g,Wlo_g,ring,rnn_out,red,2,tile,1,0,0,1048576); break;
    case 3: scan_body<2>(inp,hn,inhib,inp_weight,Whi_g,Wlo_g,ring,rnn_out,red,3,tile,0,2,0,1310720); break;
    case 4: scan_body<1>(inp,hn,inhib,inp_weight,Whi_g,Wlo_g,ring,rnn_out,red,4,tile,3,0,0,1835008); break;
    default:scan_body<2>(inp,hn,inhib,inp_weight,Whi_g,Wlo_g,ring,rnn_out,red,5,tile,4,5,0,2097152); break;
  }
}

// ============================ head kernel ============================
__global__ void head_kernel(const float* __restrict__ rnn, const float* __restrict__ fc_vec,
                            float* __restrict__ out, float* __restrict__ hn_last)
{
  int lane = threadIdx.x & 63;
  if (blockIdx.x < 4000) {
    int wid = blockIdx.x * 4 + (threadIdx.x >> 6);
    int b = wid / 1000, t = wid - b * 1000;
    const float* rp = rnn + (size_t)(b * 1000 + t) * H6 + 2560 + lane * 8;
    float4 a0 = *(const float4*)rp, a1 = *(const float4*)(rp + 4);
    const float* vp = fc_vec + lane * 8;
    float4 v0 = *(const float4*)vp, v1 = *(const float4*)(vp + 4);
    float s = a0.x*v0.x + a0.y*v0.y + a0.z*v0.z + a0.w*v0.w
            + a1.x*v1.x + a1.y*v1.y + a1.z*v1.z + a1.w*v1.w;
    for (int off = 32; off; off >>= 1) s += __shfl_down(s, off);
    if (lane == 0) out[b * 1000 + t] = 1.f / (1.f + expf(-s));
  } else {
    int idx = (blockIdx.x - 4000) * NTHR + threadIdx.x;
    int b = idx / H6, j = idx - b * H6;
    hn_last[idx] = rnn[(size_t)(b * 1000 + 999) * H6 + j];
  }
}

// ============================ x broadcast ============================
__global__ void bcast_kernel(const float* __restrict__ x,
                             float* __restrict__ x_last, float* __restrict__ x_out)
{
  int gid = blockIdx.x * blockDim.x + threadIdx.x;
  int stride = gridDim.x * blockDim.x;
  for (int i = gid; i < 12288; i += stride)
    ((float4*)x_last)[i] = ((const float4*)x)[i];
  for (int i = gid; i < 12288000; i += stride) {
    int b = i / 768000;
    int r = i - b * 768000;
    int j4 = r % 768;
    ((float4*)x_out)[i] = ((const float4*)x)[b * 768 + j4];
  }
}

// ============================ launcher ============================
extern "C" void kernel_launch(void* const* d_in, const int* in_sizes, int n_in,
                              void* d_out, int out_size, void* d_ws, size_t ws_size,
                              hipStream_t stream) {
  (void)in_sizes; (void)n_in; (void)out_size; (void)ws_size;
  const float* inp        = (const float*)d_in[0];
  const float* hn         = (const float*)d_in[1];
  const float* x          = (const float*)d_in[2];
  const float* inhib      = (const float*)d_in[3];
  /* d_in[4] = str2str_w — unused (D = -I path uses str2str_fixed) */
  const float* thal2alm_w = (const float*)d_in[5];
  const float* thal2str_w = (const float*)d_in[6];
  const float* alm2alm_w  = (const float*)d_in[7];
  const float* alm2str_w  = (const float*)d_in[8];
  const float* str2snr_w  = (const float*)d_in[9];
  const float* str2gpe_w  = (const float*)d_in[10];
  const float* gpe2stn_w  = (const float*)d_in[11];
  const float* stn2snr_w  = (const float*)d_in[12];
  const float* snr2thal_w = (const float*)d_in[13];
  const float* inp_weight = (const float*)d_in[14];
  const float* fc1        = (const float*)d_in[15];
  const float* fc2        = (const float*)d_in[16];
  const float* fixed_     = (const float*)d_in[17];

  float* out_p   = (float*)d_out;
  float* hn_last = out_p + 16000;
  float* rnn     = hn_last + 49152;
  float* x_last  = rnn + 49152000;
  float* x_out   = x_last + 49152;

  char* ws = (char*)d_ws;
  unsigned short* Whi  = (unsigned short*)(ws);
  unsigned short* Wlo  = (unsigned short*)(ws + WS_WLO);
  unsigned short* ring = (unsigned short*)(ws + WS_RING);
  float* fc_vec  = (float*)(ws + WS_FCV);

  prep_kernel<<<2048, NTHR, 0, stream>>>(hn, fixed_, thal2alm_w, thal2str_w, alm2alm_w,
      alm2str_w, str2snr_w, str2gpe_w, gpe2stn_w, stn2snr_w, snr2thal_w, fc1, fc2,
      Whi, Wlo, ring, fc_vec);
  scan_kernel<<<NWG, NTHR, 0, stream>>>(inp, hn, inhib, inp_weight,
      Whi, Wlo, ring, rnn);
  head_kernel<<<4192, NTHR, 0, stream>>>(rnn, fc_vec, out_p, hn_last);
  bcast_kernel<<<4096, NTHR, 0, stream>>>(x, x_last, x_out);
}

// Round 18
// 5901.985 us; speedup vs baseline: 1.3078x; 1.3078x over previous
//
#include <hip/hip_runtime.h>

#define H6   3072
#define TT   1000
#define NWG  192
#define NTHR 256

typedef short bf16x8 __attribute__((ext_vector_type(8)));
typedef float f32x4  __attribute__((ext_vector_type(4)));
typedef unsigned int u32x4 __attribute__((ext_vector_type(4)));

#define TAG64 0x8000800080008000ull

// ---- bf16 helpers ----
__device__ __forceinline__ unsigned short f2bf(float f) {   // RNE (weights only)
  unsigned u = __float_as_uint(f);
  return (unsigned short)((u + 0x7fffu + ((u >> 16) & 1u)) >> 16);
}
__device__ __forceinline__ float bf2f(unsigned short s) {
  return __uint_as_float(((unsigned)s) << 16);
}

// ---- workspace layout (bytes) ----
// Whi   : 2621440 bf16 = 5242880        @ 0
// Wlo   : 5242880                        @ 5242880
// ring  : 8 slots * 196608 B = 1572864   @ 10485760   (hi/lo interleaved)
// fc_v  : 512 f32 = 2048                 @ 12058624
#define WS_WLO 5242880
#define WS_RING 10485760
#define WS_FCV 12058624

// Ring slot layout (interleaved, as r6): region r: +r*32768B; chunk q: +q*2048B;
//   unit (b,g8): 32B at +b*128+g8*32 = {16B hi}{16B lo}.
// Protocol = r6 EXACTLY (best measured, 5614us): data-as-probe, per-ushort
//   parity tags, __hip_atomic_store u64 producers, no drain, no flags.
//   Ledger: nt stores +36% (r10), flag-spin +18% (r11), cross-barrier
//   speculative loads +31% via scratch spill (r12, VGPR 148 < live set 220).
// ROUND-15 CHANGE (one): PHASE-ALIGNED POLLING. The consumer's first probe
//   fires ~immediately after its reduce barrier -- before producers publish --
//   so the first 1-2 rounds are structurally wasted at ~3k cy each (the
//   measured step is ~3-4 serial coherence-visits). Pre-sleep ~2.5k cy before
//   the FIRST probe of each step (t>0), and back off 8x64cy between retries.
//   Registers/protocol untouched -> no spill, no correctness exposure.

// ============================ prep kernel ============================
__global__ void prep_kernel(
    const float* __restrict__ hn, const float* __restrict__ fixed_,
    const float* __restrict__ thal2alm_w, const float* __restrict__ thal2str_w,
    const float* __restrict__ alm2alm_w, const float* __restrict__ alm2str_w,
    const float* __restrict__ str2snr_w, const float* __restrict__ str2gpe_w,
    const float* __restrict__ gpe2stn_w, const float* __restrict__ stn2snr_w,
    const float* __restrict__ snr2thal_w,
    const float* __restrict__ fc1, const float* __restrict__ fc2,
    unsigned short* __restrict__ Whi, unsigned short* __restrict__ Wlo,
    unsigned short* __restrict__ ring, float* __restrict__ fc_vec)
{
  int gid = blockIdx.x * blockDim.x + threadIdx.x;
  int stride = gridDim.x * blockDim.x;
  const int nbt[6]  = {3,1,1,2,1,2};
  const int woff[6] = {0,786432,1048576,1310720,1835008,2097152};
  for (int idx = gid; idx < 2621440; idx += stride) {
    int u = idx >> 18;
    int t = (u<3)?0:((u<4)?1:((u<5)?2:((u<7)?3:((u<8)?4:5))));
    int local = idx - woff[t];
    int ktot = nbt[t] << 9;
    int j  = local / ktot;
    int kx = local - j*ktot;
    int bi = kx >> 9, kk = kx & 511;
    int src = j*512 + kk;
    float w;
    if (t == 0) {       // str rows: [str | thal | alm]
      if (bi == 0)      w = -fixed_[src];
      else if (bi == 1) w = (j >= 128 && j < 384) ? fmaxf(thal2str_w[src],0.f) : 0.f;
      else              w = (kk < 359) ? fmaxf(alm2str_w[src],0.f) : 0.f;
    } else if (t == 1)  w = (kk >= 256) ? -fmaxf(str2gpe_w[src],0.f) : 0.f;
    else if (t == 2)    w = -fmaxf(gpe2stn_w[src],0.f);
    else if (t == 3)    w = (bi == 0) ? ((kk < 256) ? -fmaxf(str2snr_w[src],0.f) : 0.f)
                                      : fmaxf(stn2snr_w[src],0.f);
    else if (t == 4)    w = -fmaxf(snr2thal_w[src],0.f);
    else                w = (bi == 0) ? fmaxf(thal2alm_w[src],0.f)
                                      : fmaxf(alm2alm_w[src],0.f) * ((kk < 359) ? 1.f : -1.f);
    unsigned short hi = f2bf(w);
    Whi[idx] = hi;
    Wlo[idx] = f2bf(w - bf2f(hi));
  }
  // poison slots 0-6: alternating tag bits -> any u64 has mixed parity
  for (int u = gid; u < 7*98304; u += stride)
    ring[u] = (u & 1) ? (unsigned short)0x0000 : (unsigned short)0x8000;
  // h0 = hn into slot 7 (interleaved layout), RTZ split, tag parity = 1
  for (int v = gid; v < 49152; v += stride) {
    int r    = v >> 13;
    int rem  = v & 8191;
    int q    = rem >> 9;
    int rem2 = rem & 511;
    int b    = rem2 >> 5;
    int ko   = rem2 & 31;
    int j    = (r << 9) + (q << 5) + ko;
    float val = hn[b * H6 + j];
    unsigned uh = __float_as_uint(val) >> 16;          // RTZ hi
    float lof = val - __uint_as_float(uh << 16);
    unsigned ul = __float_as_uint(lof) >> 16;          // RTZ lo (>=0)
    int off = r*16384 + q*1024 + b*64 + ((ko>>3)<<4) + (ko & 7);  // ushort idx
    ring[7*98304 + off]     = (unsigned short)(uh | 0x8000u);
    ring[7*98304 + off + 8] = (unsigned short)(ul | 0x8000u);
  }
  int wid = gid >> 6, lane = gid & 63;
  if (wid < 512) {
    float s = 0.f;
    for (int m = lane; m < 512; m += 64)
      s += fmaxf(fc1[(2560 + wid)*512 + m], 0.f) * fmaxf(fc2[m], 0.f);
    for (int off = 32; off; off >>= 1) s += __shfl_down(s, off);
    if (lane == 0) fc_vec[wid] = s;
  }
}

// ============================ scan kernel ============================
template<int NB>
__device__ __forceinline__ void scan_body(
    const float* __restrict__ inp, const float* __restrict__ hn,
    const float* __restrict__ inhib, const float* __restrict__ inp_weight,
    const unsigned short* __restrict__ Whi_g, const unsigned short* __restrict__ Wlo_g,
    unsigned short* __restrict__ ring, float* __restrict__ rnn_out,
    float* red, int type, int tile, int kb0, int kb1, int kb2, int woff)
{
  constexpr int NCW = NB * 4;                 // K-chunks (of 32) per wave
  const int tid = threadIdx.x, lane = tid & 63, wave = tid >> 6;
  const int ktot = NB << 9;
  const int jb_local = tile << 4;
  const int jb_glob  = (type << 9) + jb_local;
  const int row = lane & 15, quad = lane >> 4;

  // ---- W fragments -> registers (pinned); per-chunk ring byte offsets ----
  bf16x8 wh[NCW], wl[NCW];
  int coff[NCW];                              // byte offset within a ring slot
  {
    const unsigned short* sh = Whi_g + woff + (jb_local + row) * ktot + (quad << 3);
    const unsigned short* sl = Wlo_g + woff + (jb_local + row) * ktot + (quad << 3);
    #pragma unroll
    for (int c = 0; c < NCW; ++c) {
      int gc = wave * NCW + c;                // global chunk 0..NB*16-1
      wh[c] = *(const bf16x8*)(sh + (gc << 5));
      wl[c] = *(const bf16x8*)(sl + (gc << 5));
      int bi = gc >> 4;
      int kbv = (bi == 0) ? kb0 : ((bi == 1) ? kb1 : kb2);
      coff[c] = kbv*32768 + (gc & 15)*2048 + row*128 + quad*32;
    }
  }
  #pragma unroll
  for (int c = 0; c < NCW; ++c)
    asm volatile("" : "+v"(wh[c]), "+v"(wl[c]));

  // ---- per-lane epilogue constants (C/D: col=b=lane&15, row=quad*4+r) ----
  const int b_ep = row;
  const bool has_inp = (type == 0) && (jb_local >= 128) && (jb_local < 384);
  const int jg0 = jb_glob + (quad << 2);
  const int jl0 = jb_local + (quad << 2);
  // producer store: byte offset of hi u64 within a slot (lo at +16)
  const int qs = jl0 >> 5, kos = jl0 & 31;
  const int st_off = type*32768 + qs*2048 + b_ep*128 + ((kos>>3)<<5) + ((kos&7)<<1);
  float hprev[4], dbase[4], iw[4][4];
  #pragma unroll
  for (int r = 0; r < 4; ++r) {
    int jgr = jg0 + r;
    hprev[r] = hn[b_ep * H6 + jgr];
    float tn = ((jgr >= 512 && jgr < 1536) || (jgr >= 2048 && jgr < 2560)) ? 1.f : 0.f;
    dbase[r] = inhib[b_ep * H6 + jgr] + tn;
    #pragma unroll
    for (int i = 0; i < 4; ++i)
      iw[r][i] = has_inp ? fmaxf(inp_weight[i * H6 + jgr], 0.f) : 0.f;
  }

  for (int t = 0; t < TT; ++t) {
    const int s_rd = (t + 7) & 7;            // (t-1) mod 8 ; t=0 -> slot 7 (hn)
    const char* slotp = (const char*)ring + s_rd * 196608;
    const unsigned e32 = ((((t - 1) >> 3) & 1) ? 0x80008000u : 0u);

    float4 xi = {0.f, 0.f, 0.f, 0.f};
    if (wave == 0 && has_inp) xi = *(const float4*)(inp + (b_ep * TT + t) * 4);

    // ---- ROUND-15: phase-aligned first probe. Producers publish ~2-3k cy
    //      after our reduce barrier; probing immediately wastes 1-2 full
    //      coherence-visit rounds. Sleep ~2.5k cy first (t>0 only; t=0 data
    //      is ready from prep). ----
    if (t > 0) __builtin_amdgcn_s_sleep(40);

    // ---- poll-loads: first round all chunks, then stale-only retries ----
    u32x4 Bhi[NCW], Blo[NCW];
    unsigned todo = (NCW == 12) ? 0xFFFu : ((NCW == 8) ? 0xFFu : 0xFu);
    for (;;) {
      #pragma unroll
      for (int c = 0; c < NCW; ++c) if ((todo >> c) & 1u) {
        const char* pc = slotp + coff[c];
        asm volatile("global_load_dwordx4 %0, %2, off sc0 sc1\n\t"
                     "global_load_dwordx4 %1, %2, off offset:16 sc0 sc1"
                     : "=&v"(Bhi[c]), "=&v"(Blo[c]) : "v"(pc) : "memory");
      }
      asm volatile("s_waitcnt vmcnt(0)" ::: "memory");
      __builtin_amdgcn_sched_barrier(0);
      unsigned nt = 0;
      #pragma unroll
      for (int c = 0; c < NCW; ++c) if ((todo >> c) & 1u) {
        unsigned bad = ((Bhi[c][0] ^ e32) | (Bhi[c][1] ^ e32) |
                        (Bhi[c][2] ^ e32) | (Bhi[c][3] ^ e32) |
                        (Blo[c][0] ^ e32) | (Blo[c][1] ^ e32) |
                        (Blo[c][2] ^ e32) | (Blo[c][3] ^ e32)) & 0x80008000u;
        if (__any(bad != 0u)) nt |= 1u << c;
      }
      if (nt == 0) break;
      todo = nt;
      __builtin_amdgcn_s_sleep(8);
    }
    // strip tags (clear bit15 of every ushort)
    #pragma unroll
    for (int c = 0; c < NCW; ++c) {
      Bhi[c] &= 0x7fff7fffu;
      Blo[c] &= 0x7fff7fffu;
    }

    f32x4 acc0 = {0,0,0,0}, acc1 = {0,0,0,0}, acc2 = {0,0,0,0};
    #pragma unroll
    for (int c = 0; c < NCW; ++c) {
      bf16x8 hb = __builtin_bit_cast(bf16x8, Bhi[c]);
      bf16x8 lb = __builtin_bit_cast(bf16x8, Blo[c]);
      acc0 = __builtin_amdgcn_mfma_f32_16x16x32_bf16(wh[c], hb, acc0, 0, 0, 0);
      acc1 = __builtin_amdgcn_mfma_f32_16x16x32_bf16(wh[c], lb, acc1, 0, 0, 0);
      acc2 = __builtin_amdgcn_mfma_f32_16x16x32_bf16(wl[c], hb, acc2, 0, 0, 0);
    }
    f32x4 acc = acc0 + acc1 + acc2;

    // ---- cross-wave reduce (double-buffered on t&1; single barrier/step) ----
    float* bank = red + (t & 1) * 768;
    if (wave) *(f32x4*)(bank + ((wave - 1) * 64 + lane) * 4) = acc;
    __syncthreads();
    if (wave == 0) {
      acc = acc + *(const f32x4*)(bank + lane * 4)
                + *(const f32x4*)(bank + (64 + lane) * 4)
                + *(const f32x4*)(bank + (128 + lane) * 4);
      float proj[4] = {0.f, 0.f, 0.f, 0.f};
      if (has_inp) {
        #pragma unroll
        for (int r = 0; r < 4; ++r)
          proj[r] = xi.x*iw[r][0] + xi.y*iw[r][1] + xi.z*iw[r][2] + xi.w*iw[r][3];
      }
      const unsigned long long ptag = ((t >> 3) & 1) ? TAG64 : 0ull;
      float4 hv4;
      unsigned long long ph = 0ull, pl = 0ull;
      #pragma unroll
      for (int r = 0; r < 4; ++r) {
        float pre = hprev[r] + 0.01f * (acc[r] + dbase[r] + proj[r] - hprev[r]);
        float hv = fmaxf(pre, 0.f);
        hprev[r] = hv;
        ((float*)&hv4)[r] = hv;
        unsigned uh = __float_as_uint(hv) >> 16;          // RTZ hi (hv>=0)
        float lof = hv - __uint_as_float(uh << 16);
        unsigned ul = __float_as_uint(lof) >> 16;         // RTZ lo (lof>=0)
        ph |= ((unsigned long long)uh) << (16 * r);
        pl |= ((unsigned long long)ul) << (16 * r);
      }
      ph |= ptag; pl |= ptag;
      char* outb = (char*)ring + (t & 7) * 196608 + st_off;
      __hip_atomic_store((unsigned long long*)outb, ph,
                         __ATOMIC_RELAXED, __HIP_MEMORY_SCOPE_AGENT);
      __hip_atomic_store((unsigned long long*)(outb + 16), pl,
                         __ATOMIC_RELAXED, __HIP_MEMORY_SCOPE_AGENT);
      // no drain, no flag: consumers detect arrival via the parity tags
      *(float4*)(rnn_out + (size_t)(b_ep * TT + t) * H6 + jg0) = hv4;
    }
  }
}

__global__ void __launch_bounds__(NTHR, 1) scan_kernel(
    const float* __restrict__ inp, const float* __restrict__ hn,
    const float* __restrict__ inhib, const float* __restrict__ inp_weight,
    const unsigned short* __restrict__ Whi_g, const unsigned short* __restrict__ Wlo_g,
    unsigned short* __restrict__ ring, float* __restrict__ rnn_out)
{
  __shared__ float red[2 * 768];
  int wg = blockIdx.x;
  int type = wg >> 5, tile = wg & 31;
  switch (type) {
    case 0: scan_body<3>(inp,hn,inhib,inp_weight,Whi_g,Wlo_g,ring,rnn_out,red,0,tile,0,4,5,0);       break;
    case 1: scan_body<1>(inp,hn,inhib,inp_weight,Whi_g,Wlo_g,ring,rnn_out,red,1,tile,0,0,0,786432);  break;
    case 2: scan_body<1>(inp,hn,inhib,inp_weight,Whi_g,Wlo_g,ring,rnn_out,red,2,tile,1,0,0,1048576); break;
    case 3: scan_body<2>(inp,hn,inhib,inp_weight,Whi_g,Wlo_g,ring,rnn_out,red,3,tile,0,2,0,1310720); break;
    case 4: scan_body<1>(inp,hn,inhib,inp_weight,Whi_g,Wlo_g,ring,rnn_out,red,4,tile,3,0,0,1835008); break;
    default:scan_body<2>(inp,hn,inhib,inp_weight,Whi_g,Wlo_g,ring,rnn_out,red,5,tile,4,5,0,2097152); break;
  }
}

// ============================ head kernel ============================
__global__ void head_kernel(const float* __restrict__ rnn, const float* __restrict__ fc_vec,
                            float* __restrict__ out, float* __restrict__ hn_last)
{
  int lane = threadIdx.x & 63;
  if (blockIdx.x < 4000) {
    int wid = blockIdx.x * 4 + (threadIdx.x >> 6);
    int b = wid / 1000, t = wid - b * 1000;
    const float* rp = rnn + (size_t)(b * 1000 + t) * H6 + 2560 + lane * 8;
    float4 a0 = *(const float4*)rp, a1 = *(const float4*)(rp + 4);
    const float* vp = fc_vec + lane * 8;
    float4 v0 = *(const float4*)vp, v1 = *(const float4*)(vp + 4);
    float s = a0.x*v0.x + a0.y*v0.y + a0.z*v0.z + a0.w*v0.w
            + a1.x*v1.x + a1.y*v1.y + a1.z*v1.z + a1.w*v1.w;
    for (int off = 32; off; off >>= 1) s += __shfl_down(s, off);
    if (lane == 0) out[b * 1000 + t] = 1.f / (1.f + expf(-s));
  } else {
    int idx = (blockIdx.x - 4000) * NTHR + threadIdx.x;
    int b = idx / H6, j = idx - b * H6;
    hn_last[idx] = rnn[(size_t)(b * 1000 + 999) * H6 + j];
  }
}

// ============================ x broadcast ============================
__global__ void bcast_kernel(const float* __restrict__ x,
                             float* __restrict__ x_last, float* __restrict__ x_out)
{
  int gid = blockIdx.x * blockDim.x + threadIdx.x;
  int stride = gridDim.x * blockDim.x;
  for (int i = gid; i < 12288; i += stride)
    ((float4*)x_last)[i] = ((const float4*)x)[i];
  for (int i = gid; i < 12288000; i += stride) {
    int b = i / 768000;
    int r = i - b * 768000;
    int j4 = r % 768;
    ((float4*)x_out)[i] = ((const float4*)x)[b * 768 + j4];
  }
}

// ============================ launcher ============================
extern "C" void kernel_launch(void* const* d_in, const int* in_sizes, int n_in,
                              void* d_out, int out_size, void* d_ws, size_t ws_size,
                              hipStream_t stream) {
  (void)in_sizes; (void)n_in; (void)out_size; (void)ws_size;
  const float* inp        = (const float*)d_in[0];
  const float* hn         = (const float*)d_in[1];
  const float* x          = (const float*)d_in[2];
  const float* inhib      = (const float*)d_in[3];
  /* d_in[4] = str2str_w — unused (D = -I path uses str2str_fixed) */
  const float* thal2alm_w = (const float*)d_in[5];
  const float* thal2str_w = (const float*)d_in[6];
  const float* alm2alm_w  = (const float*)d_in[7];
  const float* alm2str_w  = (const float*)d_in[8];
  const float* str2snr_w  = (const float*)d_in[9];
  const float* str2gpe_w  = (const float*)d_in[10];
  const float* gpe2stn_w  = (const float*)d_in[11];
  const float* stn2snr_w  = (const float*)d_in[12];
  const float* snr2thal_w = (const float*)d_in[13];
  const float* inp_weight = (const float*)d_in[14];
  const float* fc1        = (const float*)d_in[15];
  const float* fc2        = (const float*)d_in[16];
  const float* fixed_     = (const float*)d_in[17];

  float* out_p   = (float*)d_out;
  float* hn_last = out_p + 16000;
  float* rnn     = hn_last + 49152;
  float* x_last  = rnn + 49152000;
  float* x_out   = x_last + 49152;

  char* ws = (char*)d_ws;
  unsigned short* Whi  = (unsigned short*)(ws);
  unsigned short* Wlo  = (unsigned short*)(ws + WS_WLO);
  unsigned short* ring = (unsigned short*)(ws + WS_RING);
  float* fc_vec  = (float*)(ws + WS_FCV);

  prep_kernel<<<2048, NTHR, 0, stream>>>(hn, fixed_, thal2alm_w, thal2str_w, alm2alm_w,
      alm2str_w, str2snr_w, str2gpe_w, gpe2stn_w, stn2snr_w, snr2thal_w, fc1, fc2,
      Whi, Wlo, ring, fc_vec);
  scan_kernel<<<NWG, NTHR, 0, stream>>>(inp, hn, inhib, inp_weight,
      Whi, Wlo, ring, rnn);
  head_kernel<<<4192, NTHR, 0, stream>>>(rnn, fc_vec, out_p, hn_last);
  bcast_kernel<<<4096, NTHR, 0, stream>>>(x, x_last, x_out);
}